// Round 2
// baseline (154.392 us; speedup 1.0000x reference)
//
#include <hip/hip_runtime.h>
#include <hip/hip_bf16.h>

// Fused spatial self-attention, B=4 C=64 H=W=64 (N=4096), fp32 in/out.
// kernel 1 = exact fp32 QKV projection, emitting q,k as split bf16 (hi+lo)
//            in (N,C) layout and v as bf16 in (C,N) layout.
// kernel 2 = flash attention with 16x16x32 bf16 MFMA; QK^T uses the 3-term
//            hi/lo product (near-fp32), softmax in fp32, PV in bf16.

using bf16x8 = __attribute__((ext_vector_type(8))) short;
using f32x4  = __attribute__((ext_vector_type(4))) float;
using us8    = __attribute__((ext_vector_type(8))) unsigned short;

static constexpr int NB = 4;     // batch
static constexpr int NC = 64;    // channels
static constexpr int NT = 4096;  // tokens (H*W)
static constexpr int PADR = 72;  // LDS row pad (bf16 elems); 144B = 9*16B

__device__ __forceinline__ unsigned short bf16bits(float f) {
    __hip_bfloat16 h = __float2bfloat16(f);
    return __builtin_bit_cast(unsigned short, h);
}
__device__ __forceinline__ float bf16f(unsigned short u) {
    return __builtin_bit_cast(float, (unsigned int)u << 16);
}

// ---------------- kernel 1: QKV projection (exact fp32) ----------------
// grid = B * (N/64) blocks, 256 threads. Each block: one batch, 64 tokens.
__global__ __launch_bounds__(256) void qkv_proj(
    const float* __restrict__ x,
    const float* __restrict__ Wq, const float* __restrict__ bq,
    const float* __restrict__ Wk, const float* __restrict__ bk,
    const float* __restrict__ Wv, const float* __restrict__ bv,
    unsigned short* __restrict__ qhi, unsigned short* __restrict__ qlo,
    unsigned short* __restrict__ khi, unsigned short* __restrict__ klo,
    unsigned short* __restrict__ vv)
{
    __shared__ float xs[64][68];   // [n][c], transposed x tile (pad 68 for b128 reads)
    __shared__ float ws[64][64];   // current projection weight [o][c]

    const int t  = threadIdx.x;
    const int b  = blockIdx.x >> 6;
    const int n0 = (blockIdx.x & 63) << 6;

    // stage x tile transposed: all 64 channels x 64 tokens (4096 floats,
    // 256 threads x 4 iters x float4).  (Round-1 bugfix: was 1 iter -> only
    // channels 0..15 staged, rest of xs uninitialized.)
    #pragma unroll
    for (int i = 0; i < 4; ++i) {
        const int idx = i * 256 + t;
        const int c = idx >> 4, n4 = (idx & 15) << 2;
        const float4 xv = *reinterpret_cast<const float4*>(
            x + ((size_t)(b * NC + c)) * NT + n0 + n4);
        xs[n4 + 0][c] = xv.x; xs[n4 + 1][c] = xv.y;
        xs[n4 + 2][c] = xv.z; xs[n4 + 3][c] = xv.w;
    }

    const int n  = t & 63;          // token within tile (lane)
    const int ob = (t >> 6) << 4;   // wave -> block of 16 output channels

    for (int p = 0; p < 3; ++p) {
        const float* Wp = (p == 0) ? Wq : (p == 1) ? Wk : Wv;
        const float* bp = (p == 0) ? bq : (p == 1) ? bk : bv;
        __syncthreads();   // covers xs staging at p==0; ws reuse for p>0
        #pragma unroll
        for (int i = 0; i < 4; ++i)
            reinterpret_cast<float4*>(&ws[0][0])[i * 256 + t] =
                reinterpret_cast<const float4*>(Wp)[i * 256 + t];
        __syncthreads();

        float acc[16];
        #pragma unroll
        for (int oo = 0; oo < 16; ++oo) acc[oo] = bp[ob + oo];
        for (int c4 = 0; c4 < 16; ++c4) {
            const float4 xv = *reinterpret_cast<const float4*>(&xs[n][c4 * 4]);
            #pragma unroll
            for (int oo = 0; oo < 16; ++oo) {
                const float4 wv = *reinterpret_cast<const float4*>(&ws[ob + oo][c4 * 4]);
                acc[oo] = fmaf(wv.x, xv.x, acc[oo]);
                acc[oo] = fmaf(wv.y, xv.y, acc[oo]);
                acc[oo] = fmaf(wv.z, xv.z, acc[oo]);
                acc[oo] = fmaf(wv.w, xv.w, acc[oo]);
            }
        }

        if (p < 2) {  // q, k: split hi/lo bf16, (N,C) layout
            unsigned short* hp = (p == 0) ? qhi : khi;
            unsigned short* lp = (p == 0) ? qlo : klo;
            unsigned short hb[16], lb[16];
            #pragma unroll
            for (int oo = 0; oo < 16; ++oo) {
                const float a = acc[oo];
                const unsigned short h = bf16bits(a);
                hb[oo] = h;
                lb[oo] = bf16bits(a - bf16f(h));
            }
            const size_t base = ((size_t)(b * NT + n0 + n)) * NC + ob;
            *reinterpret_cast<us8*>(hp + base)     = *reinterpret_cast<const us8*>(&hb[0]);
            *reinterpret_cast<us8*>(hp + base + 8) = *reinterpret_cast<const us8*>(&hb[8]);
            *reinterpret_cast<us8*>(lp + base)     = *reinterpret_cast<const us8*>(&lb[0]);
            *reinterpret_cast<us8*>(lp + base + 8) = *reinterpret_cast<const us8*>(&lb[8]);
        } else {      // v: plain bf16, (C,N) layout (coalesced per-oo stores)
            const size_t vbase = (size_t)b * NC * NT + n0 + n;
            #pragma unroll
            for (int oo = 0; oo < 16; ++oo)
                vv[vbase + (size_t)(ob + oo) * NT] = bf16bits(acc[oo]);
        }
    }
}

// ---------------- kernel 2: flash attention ----------------
// grid = B * (N/64), 256 threads = 4 waves; wave w owns query rows
// i0 + 16w .. +15. j-tiles of 64 keys, reg-staged prefetch into LDS.
__global__ __launch_bounds__(256) void attn_fused(
    const unsigned short* __restrict__ qhi, const unsigned short* __restrict__ qlo,
    const unsigned short* __restrict__ khi, const unsigned short* __restrict__ klo,
    const unsigned short* __restrict__ vv, float* __restrict__ out)
{
    __shared__ unsigned short khs[64 * PADR];      // K-tile hi  [j][c]
    __shared__ unsigned short kls[64 * PADR];      // K-tile lo  [j][c]
    __shared__ unsigned short vs_[64 * PADR];      // V-tile     [c][j]
    __shared__ unsigned short ps[4][16 * PADR];    // per-wave P [i][j]

    const int t    = threadIdx.x;
    const int lane = t & 63;
    const int wv   = t >> 6;
    const int b    = blockIdx.x >> 6;
    const int i0   = (blockIdx.x & 63) << 6;
    const int c0   = lane & 15;   // A-row / B-col within subtile
    const int g    = lane >> 4;   // k-group 0..3

    // Q fragments, held in registers for the whole kernel.
    // A-frag (16x16x32): lane holds row (lane&15), k = (lane>>4)*8 + [0..7].
    bf16x8 qh[2], ql[2];
    {
        const size_t qoff = ((size_t)(b * NT + i0 + wv * 16 + c0)) * NC + g * 8;
        qh[0] = *reinterpret_cast<const bf16x8*>(qhi + qoff);
        qh[1] = *reinterpret_cast<const bf16x8*>(qhi + qoff + 32);
        ql[0] = *reinterpret_cast<const bf16x8*>(qlo + qoff);
        ql[1] = *reinterpret_cast<const bf16x8*>(qlo + qoff + 32);
    }

    f32x4 acc[4] = {{0.f,0.f,0.f,0.f},{0.f,0.f,0.f,0.f},
                    {0.f,0.f,0.f,0.f},{0.f,0.f,0.f,0.f}};
    float m[4] = {-INFINITY, -INFINITY, -INFINITY, -INFINITY};
    float l[4] = {0.f, 0.f, 0.f, 0.f};

    // staging: 512 chunks of 8 bf16 per 64x64 tile; thread handles t and t+256
    const int ja = t >> 3,        ca = t & 7;            // chunk t
    const int jb2 = (t + 256) >> 3, cb2 = (t + 256) & 7; // chunk t+256
    const unsigned short* kh_g = khi + (size_t)b * NT * NC;
    const unsigned short* kl_g = klo + (size_t)b * NT * NC;
    const unsigned short* v_g  = vv  + (size_t)b * NC * NT;

    bf16x8 st0, st1, st2, st3, st4, st5;
    auto stage_load = [&](int j0) {
        st0 = *reinterpret_cast<const bf16x8*>(kh_g + (size_t)(j0 + ja) * NC + ca * 8);
        st1 = *reinterpret_cast<const bf16x8*>(kh_g + (size_t)(j0 + jb2) * NC + cb2 * 8);
        st2 = *reinterpret_cast<const bf16x8*>(kl_g + (size_t)(j0 + ja) * NC + ca * 8);
        st3 = *reinterpret_cast<const bf16x8*>(kl_g + (size_t)(j0 + jb2) * NC + cb2 * 8);
        // v tile: row = channel, col = token chunk
        st4 = *reinterpret_cast<const bf16x8*>(v_g + (size_t)ja * NT + j0 + ca * 8);
        st5 = *reinterpret_cast<const bf16x8*>(v_g + (size_t)jb2 * NT + j0 + cb2 * 8);
    };

    stage_load(0);

    for (int jt = 0; jt < NT / 64; ++jt) {
        __syncthreads();   // previous tile's LDS reads complete
        *reinterpret_cast<bf16x8*>(&khs[ja * PADR + ca * 8])   = st0;
        *reinterpret_cast<bf16x8*>(&khs[jb2 * PADR + cb2 * 8]) = st1;
        *reinterpret_cast<bf16x8*>(&kls[ja * PADR + ca * 8])   = st2;
        *reinterpret_cast<bf16x8*>(&kls[jb2 * PADR + cb2 * 8]) = st3;
        *reinterpret_cast<bf16x8*>(&vs_[ja * PADR + ca * 8])   = st4;
        *reinterpret_cast<bf16x8*>(&vs_[jb2 * PADR + cb2 * 8]) = st5;
        __syncthreads();
        if (jt + 1 < NT / 64) stage_load((jt + 1) * 64);  // in flight under compute

        // ---- S = Q K^T (hi*hi + lo*hi + hi*lo : near-fp32) ----
        f32x4 s[4] = {{0.f,0.f,0.f,0.f},{0.f,0.f,0.f,0.f},
                      {0.f,0.f,0.f,0.f},{0.f,0.f,0.f,0.f}};
        #pragma unroll
        for (int js = 0; js < 4; ++js) {
            #pragma unroll
            for (int kb = 0; kb < 2; ++kb) {
                const int roff = (js * 16 + c0) * PADR + kb * 32 + g * 8;
                const bf16x8 bh = *reinterpret_cast<const bf16x8*>(&khs[roff]);
                const bf16x8 bl = *reinterpret_cast<const bf16x8*>(&kls[roff]);
                s[js] = __builtin_amdgcn_mfma_f32_16x16x32_bf16(qh[kb], bh, s[js], 0, 0, 0);
                s[js] = __builtin_amdgcn_mfma_f32_16x16x32_bf16(ql[kb], bh, s[js], 0, 0, 0);
                s[js] = __builtin_amdgcn_mfma_f32_16x16x32_bf16(qh[kb], bl, s[js], 0, 0, 0);
            }
        }

        // ---- online softmax (D layout: col = lane&15 = key, row = g*4+r = query) ----
        float mt[4], pr[4][4], rs[4], sc[4];
        #pragma unroll
        for (int r = 0; r < 4; ++r)
            mt[r] = fmaxf(fmaxf(s[0][r], s[1][r]), fmaxf(s[2][r], s[3][r]));
        #pragma unroll
        for (int d = 1; d < 16; d <<= 1) {
            #pragma unroll
            for (int r = 0; r < 4; ++r)
                mt[r] = fmaxf(mt[r], __shfl_xor(mt[r], d));
        }
        #pragma unroll
        for (int r = 0; r < 4; ++r) {
            const float mn = fmaxf(m[r], mt[r]);
            sc[r] = __expf(m[r] - mn);
            m[r] = mn;
            rs[r] = 0.f;
            #pragma unroll
            for (int js = 0; js < 4; ++js) {
                pr[js][r] = __expf(s[js][r] - mn);
                rs[r] += pr[js][r];
            }
        }
        #pragma unroll
        for (int d = 1; d < 16; d <<= 1) {
            #pragma unroll
            for (int r = 0; r < 4; ++r)
                rs[r] += __shfl_xor(rs[r], d);
        }
        #pragma unroll
        for (int r = 0; r < 4; ++r) l[r] = l[r] * sc[r] + rs[r];
        #pragma unroll
        for (int cs = 0; cs < 4; ++cs)
            #pragma unroll
            for (int r = 0; r < 4; ++r)
                acc[cs][r] *= sc[r];

        // ---- P -> LDS (bf16), per-wave buffer (no barrier: in-wave DS order) ----
        #pragma unroll
        for (int js = 0; js < 4; ++js)
            #pragma unroll
            for (int r = 0; r < 4; ++r)
                ps[wv][(g * 4 + r) * PADR + js * 16 + c0] = bf16bits(pr[js][r]);

        // ---- O += P V ----
        #pragma unroll
        for (int jb = 0; jb < 2; ++jb) {
            const bf16x8 ap = *reinterpret_cast<const bf16x8*>(
                &ps[wv][c0 * PADR + jb * 32 + g * 8]);
            #pragma unroll
            for (int cs = 0; cs < 4; ++cs) {
                const bf16x8 bvv = *reinterpret_cast<const bf16x8*>(
                    &vs_[(cs * 16 + c0) * PADR + jb * 32 + g * 8]);
                acc[cs] = __builtin_amdgcn_mfma_f32_16x16x32_bf16(ap, bvv, acc[cs], 0, 0, 0);
            }
        }
    }

    // ---- epilogue: normalize, write out (B,C,N) fp32 ----
    #pragma unroll
    for (int r = 0; r < 4; ++r) l[r] = 1.f / l[r];
    const int irow = i0 + wv * 16 + g * 4;
    #pragma unroll
    for (int cs = 0; cs < 4; ++cs)
        #pragma unroll
        for (int r = 0; r < 4; ++r)
            out[(size_t)b * NC * NT + (size_t)(cs * 16 + c0) * NT + irow + r] =
                acc[cs][r] * l[r];
}

extern "C" void kernel_launch(void* const* d_in, const int* in_sizes, int n_in,
                              void* d_out, int out_size, void* d_ws, size_t ws_size,
                              hipStream_t stream)
{
    const float* x  = (const float*)d_in[0];
    const float* Wq = (const float*)d_in[1];
    const float* bq = (const float*)d_in[2];
    const float* Wk = (const float*)d_in[3];
    const float* bk = (const float*)d_in[4];
    const float* Wv = (const float*)d_in[5];
    const float* bv = (const float*)d_in[6];
    float* out = (float*)d_out;

    // workspace carve: qhi,qlo,khi,klo ((N,C) bf16) + v ((C,N) bf16) = 10 MB
    const size_t S = (size_t)NB * NT * NC;
    unsigned short* qhi = (unsigned short*)d_ws;
    unsigned short* qlo = qhi + S;
    unsigned short* khi = qlo + S;
    unsigned short* klo = khi + S;
    unsigned short* vvp = klo + S;

    qkv_proj<<<NB * (NT / 64), 256, 0, stream>>>(x, Wq, bq, Wk, bk, Wv, bv,
                                                 qhi, qlo, khi, klo, vvp);
    attn_fused<<<NB * (NT / 64), 256, 0, stream>>>(qhi, qlo, khi, klo, vvp, out);
}

// Round 3
// 100.953 us; speedup vs baseline: 1.5293x; 1.5293x over previous
//
#include <hip/hip_runtime.h>
#include <hip/hip_bf16.h>

// Fused spatial self-attention, B=4 C=64 H=W=64 (N=4096), fp32 in/out.
// kernel 1 = exact fp32 QKV projection (split across 3*256 blocks), emitting
//            q,k as split bf16 (hi+lo) in (N,C) layout, v bf16 in (C,N).
// kernel 2 = flash attention, split-j x4 (flash-decoding) for occupancy:
//            1024 blocks x 4 waves; partials (bf16 acc, f32 m/l) in ws.
// kernel 3 = merge partials -> fp32 out.

using bf16x8 = __attribute__((ext_vector_type(8))) short;
using f32x4  = __attribute__((ext_vector_type(4))) float;
using us8    = __attribute__((ext_vector_type(8))) unsigned short;

static constexpr int NB = 4;     // batch
static constexpr int NC = 64;    // channels
static constexpr int NT = 4096;  // tokens (H*W)
static constexpr int PADR = 72;  // LDS row pad (bf16 elems); 144B = 9*16B

__device__ __forceinline__ unsigned short bf16bits(float f) {
    __hip_bfloat16 h = __float2bfloat16(f);
    return __builtin_bit_cast(unsigned short, h);
}
__device__ __forceinline__ float bf16f(unsigned short u) {
    return __builtin_bit_cast(float, (unsigned int)u << 16);
}

// ---------------- kernel 1: QKV projection (exact fp32) ----------------
// grid = 3 * B * (N/64); blockIdx>>8 selects projection (q/k/v).
__global__ __launch_bounds__(256) void qkv_proj(
    const float* __restrict__ x,
    const float* __restrict__ Wq, const float* __restrict__ bq,
    const float* __restrict__ Wk, const float* __restrict__ bk,
    const float* __restrict__ Wv, const float* __restrict__ bv,
    unsigned short* __restrict__ qhi, unsigned short* __restrict__ qlo,
    unsigned short* __restrict__ khi, unsigned short* __restrict__ klo,
    unsigned short* __restrict__ vv)
{
    __shared__ float xs[64][68];   // [n][c], transposed x tile (pad for b128)
    __shared__ float ws[64][64];   // projection weight [o][c]

    const int t  = threadIdx.x;
    const int p  = blockIdx.x >> 8;          // 0=q 1=k 2=v
    const int b  = (blockIdx.x >> 6) & 3;
    const int n0 = (blockIdx.x & 63) << 6;

    const float* Wp = (p == 0) ? Wq : (p == 1) ? Wk : Wv;
    const float* bp = (p == 0) ? bq : (p == 1) ? bk : bv;

    // stage x tile transposed: 64 channels x 64 tokens
    #pragma unroll
    for (int i = 0; i < 4; ++i) {
        const int idx = i * 256 + t;
        const int c = idx >> 4, n4 = (idx & 15) << 2;
        const float4 xv = *reinterpret_cast<const float4*>(
            x + ((size_t)(b * NC + c)) * NT + n0 + n4);
        xs[n4 + 0][c] = xv.x; xs[n4 + 1][c] = xv.y;
        xs[n4 + 2][c] = xv.z; xs[n4 + 3][c] = xv.w;
    }
    #pragma unroll
    for (int i = 0; i < 4; ++i)
        reinterpret_cast<float4*>(&ws[0][0])[i * 256 + t] =
            reinterpret_cast<const float4*>(Wp)[i * 256 + t];
    __syncthreads();

    const int n  = t & 63;          // token within tile
    const int ob = (t >> 6) << 4;   // wave -> block of 16 output channels

    float acc[16];
    #pragma unroll
    for (int oo = 0; oo < 16; ++oo) acc[oo] = bp[ob + oo];
    for (int c4 = 0; c4 < 16; ++c4) {
        const float4 xv = *reinterpret_cast<const float4*>(&xs[n][c4 * 4]);
        #pragma unroll
        for (int oo = 0; oo < 16; ++oo) {
            const float4 wv = *reinterpret_cast<const float4*>(&ws[ob + oo][c4 * 4]);
            acc[oo] = fmaf(wv.x, xv.x, acc[oo]);
            acc[oo] = fmaf(wv.y, xv.y, acc[oo]);
            acc[oo] = fmaf(wv.z, xv.z, acc[oo]);
            acc[oo] = fmaf(wv.w, xv.w, acc[oo]);
        }
    }

    if (p < 2) {  // q, k: split hi/lo bf16, (N,C) layout
        unsigned short* hp = (p == 0) ? qhi : khi;
        unsigned short* lp = (p == 0) ? qlo : klo;
        unsigned short hb[16], lb[16];
        #pragma unroll
        for (int oo = 0; oo < 16; ++oo) {
            const float a = acc[oo];
            const unsigned short h = bf16bits(a);
            hb[oo] = h;
            lb[oo] = bf16bits(a - bf16f(h));
        }
        const size_t base = ((size_t)(b * NT + n0 + n)) * NC + ob;
        *reinterpret_cast<us8*>(hp + base)     = *reinterpret_cast<const us8*>(&hb[0]);
        *reinterpret_cast<us8*>(hp + base + 8) = *reinterpret_cast<const us8*>(&hb[8]);
        *reinterpret_cast<us8*>(lp + base)     = *reinterpret_cast<const us8*>(&lb[0]);
        *reinterpret_cast<us8*>(lp + base + 8) = *reinterpret_cast<const us8*>(&lb[8]);
    } else {      // v: plain bf16, (C,N) layout
        const size_t vbase = (size_t)b * NC * NT + n0 + n;
        #pragma unroll
        for (int oo = 0; oo < 16; ++oo)
            vv[vbase + (size_t)(ob + oo) * NT] = bf16bits(acc[oo]);
    }
}

// ---------------- kernel 2: flash attention (split-j) ----------------
// grid = splits * B * (N/64); blockIdx>>8 = split index s; each block does
// nTiles = (N/64)/splits j-tiles starting at s*nTiles.
__global__ __launch_bounds__(256) void attn_fused(
    const unsigned short* __restrict__ qhi, const unsigned short* __restrict__ qlo,
    const unsigned short* __restrict__ khi, const unsigned short* __restrict__ klo,
    const unsigned short* __restrict__ vv, float* __restrict__ out,
    unsigned short* __restrict__ pacc, float* __restrict__ pm,
    float* __restrict__ pl, int nTiles, int direct)
{
    __shared__ unsigned short khs[64 * PADR];      // K-tile hi  [j][c]
    __shared__ unsigned short kls[64 * PADR];      // K-tile lo  [j][c]
    __shared__ unsigned short vs_[64 * PADR];      // V-tile     [c][j]
    __shared__ unsigned short ps[4][16 * PADR];    // per-wave P [i][j]

    const int t    = threadIdx.x;
    const int lane = t & 63;
    const int wv   = t >> 6;
    const int s    = blockIdx.x >> 8;
    const int b    = (blockIdx.x >> 6) & 3;
    const int i0   = (blockIdx.x & 63) << 6;
    const int c0   = lane & 15;   // A-row / B-col within subtile
    const int g    = lane >> 4;   // k-group 0..3

    // Q fragments (A-frag 16x16x32: lane row = lane&15, k = (lane>>4)*8+[0..7])
    bf16x8 qh[2], ql[2];
    {
        const size_t qoff = ((size_t)(b * NT + i0 + wv * 16 + c0)) * NC + g * 8;
        qh[0] = *reinterpret_cast<const bf16x8*>(qhi + qoff);
        qh[1] = *reinterpret_cast<const bf16x8*>(qhi + qoff + 32);
        ql[0] = *reinterpret_cast<const bf16x8*>(qlo + qoff);
        ql[1] = *reinterpret_cast<const bf16x8*>(qlo + qoff + 32);
    }

    f32x4 acc[4] = {{0.f,0.f,0.f,0.f},{0.f,0.f,0.f,0.f},
                    {0.f,0.f,0.f,0.f},{0.f,0.f,0.f,0.f}};
    float m[4] = {-INFINITY, -INFINITY, -INFINITY, -INFINITY};
    float l[4] = {0.f, 0.f, 0.f, 0.f};

    // staging: 512 chunks of 8 bf16 per 64x64 tile; thread handles t and t+256
    const int ja = t >> 3,         ca = t & 7;
    const int jb2 = (t + 256) >> 3, cb2 = (t + 256) & 7;
    const unsigned short* kh_g = khi + (size_t)b * NT * NC;
    const unsigned short* kl_g = klo + (size_t)b * NT * NC;
    const unsigned short* v_g  = vv  + (size_t)b * NC * NT;

    bf16x8 st0, st1, st2, st3, st4, st5;
    auto stage_load = [&](int j0) {
        st0 = *reinterpret_cast<const bf16x8*>(kh_g + (size_t)(j0 + ja) * NC + ca * 8);
        st1 = *reinterpret_cast<const bf16x8*>(kh_g + (size_t)(j0 + jb2) * NC + cb2 * 8);
        st2 = *reinterpret_cast<const bf16x8*>(kl_g + (size_t)(j0 + ja) * NC + ca * 8);
        st3 = *reinterpret_cast<const bf16x8*>(kl_g + (size_t)(j0 + jb2) * NC + cb2 * 8);
        st4 = *reinterpret_cast<const bf16x8*>(v_g + (size_t)ja * NT + j0 + ca * 8);
        st5 = *reinterpret_cast<const bf16x8*>(v_g + (size_t)jb2 * NT + j0 + cb2 * 8);
    };

    const int t0 = s * nTiles;
    stage_load(t0 * 64);

    for (int k = 0; k < nTiles; ++k) {
        const int jt = t0 + k;
        __syncthreads();   // previous tile's LDS reads complete
        *reinterpret_cast<bf16x8*>(&khs[ja * PADR + ca * 8])   = st0;
        *reinterpret_cast<bf16x8*>(&khs[jb2 * PADR + cb2 * 8]) = st1;
        *reinterpret_cast<bf16x8*>(&kls[ja * PADR + ca * 8])   = st2;
        *reinterpret_cast<bf16x8*>(&kls[jb2 * PADR + cb2 * 8]) = st3;
        *reinterpret_cast<bf16x8*>(&vs_[ja * PADR + ca * 8])   = st4;
        *reinterpret_cast<bf16x8*>(&vs_[jb2 * PADR + cb2 * 8]) = st5;
        __syncthreads();
        if (k + 1 < nTiles) stage_load((jt + 1) * 64);  // in flight under compute

        // ---- S = Q K^T (hi*hi + lo*hi + hi*lo : near-fp32) ----
        f32x4 sreg[4] = {{0.f,0.f,0.f,0.f},{0.f,0.f,0.f,0.f},
                         {0.f,0.f,0.f,0.f},{0.f,0.f,0.f,0.f}};
        #pragma unroll
        for (int js = 0; js < 4; ++js) {
            #pragma unroll
            for (int kb = 0; kb < 2; ++kb) {
                const int roff = (js * 16 + c0) * PADR + kb * 32 + g * 8;
                const bf16x8 bh = *reinterpret_cast<const bf16x8*>(&khs[roff]);
                const bf16x8 bl = *reinterpret_cast<const bf16x8*>(&kls[roff]);
                sreg[js] = __builtin_amdgcn_mfma_f32_16x16x32_bf16(qh[kb], bh, sreg[js], 0, 0, 0);
                sreg[js] = __builtin_amdgcn_mfma_f32_16x16x32_bf16(ql[kb], bh, sreg[js], 0, 0, 0);
                sreg[js] = __builtin_amdgcn_mfma_f32_16x16x32_bf16(qh[kb], bl, sreg[js], 0, 0, 0);
            }
        }

        // ---- online softmax (D: col = lane&15 = key, row = g*4+r = query) ----
        float mt[4], pr[4][4], rs[4], sc[4];
        #pragma unroll
        for (int r = 0; r < 4; ++r)
            mt[r] = fmaxf(fmaxf(sreg[0][r], sreg[1][r]), fmaxf(sreg[2][r], sreg[3][r]));
        #pragma unroll
        for (int d = 1; d < 16; d <<= 1) {
            #pragma unroll
            for (int r = 0; r < 4; ++r)
                mt[r] = fmaxf(mt[r], __shfl_xor(mt[r], d));
        }
        #pragma unroll
        for (int r = 0; r < 4; ++r) {
            const float mn = fmaxf(m[r], mt[r]);
            sc[r] = __expf(m[r] - mn);
            m[r] = mn;
            rs[r] = 0.f;
            #pragma unroll
            for (int js = 0; js < 4; ++js) {
                pr[js][r] = __expf(sreg[js][r] - mn);
                rs[r] += pr[js][r];
            }
        }
        #pragma unroll
        for (int d = 1; d < 16; d <<= 1) {
            #pragma unroll
            for (int r = 0; r < 4; ++r)
                rs[r] += __shfl_xor(rs[r], d);
        }
        #pragma unroll
        for (int r = 0; r < 4; ++r) l[r] = l[r] * sc[r] + rs[r];
        #pragma unroll
        for (int cs = 0; cs < 4; ++cs)
            #pragma unroll
            for (int r = 0; r < 4; ++r)
                acc[cs][r] *= sc[r];

        // ---- P -> LDS (bf16), per-wave buffer (in-wave DS ordering) ----
        #pragma unroll
        for (int js = 0; js < 4; ++js)
            #pragma unroll
            for (int r = 0; r < 4; ++r)
                ps[wv][(g * 4 + r) * PADR + js * 16 + c0] = bf16bits(pr[js][r]);

        // ---- O += P V ----
        #pragma unroll
        for (int jb = 0; jb < 2; ++jb) {
            const bf16x8 ap = *reinterpret_cast<const bf16x8*>(
                &ps[wv][c0 * PADR + jb * 32 + g * 8]);
            #pragma unroll
            for (int cs = 0; cs < 4; ++cs) {
                const bf16x8 bvv = *reinterpret_cast<const bf16x8*>(
                    &vs_[(cs * 16 + c0) * PADR + jb * 32 + g * 8]);
                acc[cs] = __builtin_amdgcn_mfma_f32_16x16x32_bf16(ap, bvv, acc[cs], 0, 0, 0);
            }
        }
    }

    // ---- epilogue ----
    const int irow = i0 + wv * 16 + g * 4;
    if (direct) {
        float linv[4];
        #pragma unroll
        for (int r = 0; r < 4; ++r) linv[r] = 1.f / l[r];
        #pragma unroll
        for (int cs = 0; cs < 4; ++cs)
            #pragma unroll
            for (int r = 0; r < 4; ++r)
                out[(size_t)b * NC * NT + (size_t)(cs * 16 + c0) * NT + irow + r] =
                    acc[cs][r] * linv[r];
    } else {
        const size_t pb = (size_t)(s * NB + b);
        #pragma unroll
        for (int cs = 0; cs < 4; ++cs)
            #pragma unroll
            for (int r = 0; r < 4; ++r)
                pacc[(pb * NC + cs * 16 + c0) * NT + irow + r] = bf16bits(acc[cs][r]);
        if (c0 == 0) {
            #pragma unroll
            for (int r = 0; r < 4; ++r) {
                pm[pb * NT + irow + r] = m[r];
                pl[pb * NT + irow + r] = l[r];
            }
        }
    }
}

// ---------------- kernel 3: merge split-j partials ----------------
// grid = B * C * (N/256), 256 threads; thread -> one (b,c,i) output.
__global__ __launch_bounds__(256) void merge_partials(
    const unsigned short* __restrict__ pacc, const float* __restrict__ pm,
    const float* __restrict__ pl, float* __restrict__ out, int splits)
{
    const int t = threadIdx.x;
    const int i = ((blockIdx.x & 15) << 8) + t;
    const int c = (blockIdx.x >> 4) & 63;
    const int b = blockIdx.x >> 10;

    float ms[8];
    float M = -INFINITY;
    for (int s = 0; s < splits; ++s) {
        ms[s] = pm[(size_t)(s * NB + b) * NT + i];
        M = fmaxf(M, ms[s]);
    }
    float L = 0.f, A = 0.f;
    for (int s = 0; s < splits; ++s) {
        const float w = __expf(ms[s] - M);
        L += w * pl[(size_t)(s * NB + b) * NT + i];
        A += w * bf16f(pacc[((size_t)(s * NB + b) * NC + c) * NT + i]);
    }
    out[((size_t)b * NC + c) * NT + i] = A / L;
}

extern "C" void kernel_launch(void* const* d_in, const int* in_sizes, int n_in,
                              void* d_out, int out_size, void* d_ws, size_t ws_size,
                              hipStream_t stream)
{
    const float* x  = (const float*)d_in[0];
    const float* Wq = (const float*)d_in[1];
    const float* bq = (const float*)d_in[2];
    const float* Wk = (const float*)d_in[3];
    const float* bk = (const float*)d_in[4];
    const float* Wv = (const float*)d_in[5];
    const float* bv = (const float*)d_in[6];
    float* out = (float*)d_out;

    // ws carve: qhi,qlo,khi,klo ((N,C) bf16) + v ((C,N) bf16) = 10 MB base,
    // then split-j partials (bf16 acc + f32 m,l per split).
    const size_t S = (size_t)NB * NT * NC;           // 1M elements
    const size_t base_bytes = 10 * S;                // 5 bf16 arrays
    auto fits = [&](int sp) {
        return base_bytes + (size_t)sp * (2 * S + 2 * 4 * (size_t)NB * NT) <= ws_size;
    };
    const int splits = fits(4) ? 4 : fits(2) ? 2 : fits(1) ? 1 : 0;

    unsigned short* qhi = (unsigned short*)d_ws;
    unsigned short* qlo = qhi + S;
    unsigned short* khi = qlo + S;
    unsigned short* klo = khi + S;
    unsigned short* vvp = klo + S;

    qkv_proj<<<3 * NB * (NT / 64), 256, 0, stream>>>(x, Wq, bq, Wk, bk, Wv, bv,
                                                     qhi, qlo, khi, klo, vvp);

    if (splits == 0) {
        attn_fused<<<NB * (NT / 64), 256, 0, stream>>>(
            qhi, qlo, khi, klo, vvp, out, nullptr, nullptr, nullptr, NT / 64, 1);
        return;
    }

    unsigned short* pacc = vvp + S;
    float* pm = (float*)(pacc + (size_t)splits * S);
    float* pl = pm + (size_t)splits * NB * NT;

    attn_fused<<<splits * NB * (NT / 64), 256, 0, stream>>>(
        qhi, qlo, khi, klo, vvp, out, pacc, pm, pl, (NT / 64) / splits, 0);
    merge_partials<<<NB * NC * (NT / 256), 256, 0, stream>>>(pacc, pm, pl, out, splits);
}

// Round 4
// 84.874 us; speedup vs baseline: 1.8191x; 1.1894x over previous
//
#include <hip/hip_runtime.h>
#include <hip/hip_bf16.h>

// Fused spatial self-attention, B=4 C=64 H=W=64 (N=4096), fp32 in/out.
// Round 4: all-fp16 datapath. kernel 1 = exact fp32 QKV projection -> q,k
// (N,C) fp16, v (C,N) fp16. kernel 2 = flash attention, split-j x4,
// single-term fp16 16x16x32 MFMA QK^T, fp32 softmax, fp16 PV; partials
// stored NORMALIZED (o_s fp16, m/l f32). kernel 3 = merge.

using f16    = _Float16;
using f16x8  = __attribute__((ext_vector_type(8))) f16;
using f32x4  = __attribute__((ext_vector_type(4))) float;

static constexpr int NB = 4;     // batch
static constexpr int NC = 64;    // channels
static constexpr int NT = 4096;  // tokens (H*W)
static constexpr int PADR = 72;  // LDS row pad (elems); 144B = 9*16B

// ---------------- kernel 1: QKV projection (exact fp32) ----------------
// grid = 3 * B * (N/64); blockIdx>>8 selects projection (q/k/v).
__global__ __launch_bounds__(256) void qkv_proj(
    const float* __restrict__ x,
    const float* __restrict__ Wq, const float* __restrict__ bq,
    const float* __restrict__ Wk, const float* __restrict__ bk,
    const float* __restrict__ Wv, const float* __restrict__ bv,
    f16* __restrict__ qh, f16* __restrict__ kh, f16* __restrict__ vv)
{
    __shared__ float xs[64][68];   // [n][c], transposed x tile (pad for b128)
    __shared__ float ws[64][64];   // projection weight [o][c]

    const int t  = threadIdx.x;
    const int p  = blockIdx.x >> 8;          // 0=q 1=k 2=v
    const int b  = (blockIdx.x >> 6) & 3;
    const int n0 = (blockIdx.x & 63) << 6;

    const float* Wp = (p == 0) ? Wq : (p == 1) ? Wk : Wv;
    const float* bp = (p == 0) ? bq : (p == 1) ? bk : bv;

    #pragma unroll
    for (int i = 0; i < 4; ++i) {
        const int idx = i * 256 + t;
        const int c = idx >> 4, n4 = (idx & 15) << 2;
        const float4 xv = *reinterpret_cast<const float4*>(
            x + ((size_t)(b * NC + c)) * NT + n0 + n4);
        xs[n4 + 0][c] = xv.x; xs[n4 + 1][c] = xv.y;
        xs[n4 + 2][c] = xv.z; xs[n4 + 3][c] = xv.w;
    }
    #pragma unroll
    for (int i = 0; i < 4; ++i)
        reinterpret_cast<float4*>(&ws[0][0])[i * 256 + t] =
            reinterpret_cast<const float4*>(Wp)[i * 256 + t];
    __syncthreads();

    const int n  = t & 63;          // token within tile
    const int ob = (t >> 6) << 4;   // wave -> block of 16 output channels

    float acc[16];
    #pragma unroll
    for (int oo = 0; oo < 16; ++oo) acc[oo] = bp[ob + oo];
    for (int c4 = 0; c4 < 16; ++c4) {
        const float4 xv = *reinterpret_cast<const float4*>(&xs[n][c4 * 4]);
        #pragma unroll
        for (int oo = 0; oo < 16; ++oo) {
            const float4 wv = *reinterpret_cast<const float4*>(&ws[ob + oo][c4 * 4]);
            acc[oo] = fmaf(wv.x, xv.x, acc[oo]);
            acc[oo] = fmaf(wv.y, xv.y, acc[oo]);
            acc[oo] = fmaf(wv.z, xv.z, acc[oo]);
            acc[oo] = fmaf(wv.w, xv.w, acc[oo]);
        }
    }

    if (p < 2) {  // q, k: fp16, (N,C) layout
        f16* hp = (p == 0) ? qh : kh;
        f16 hb[16];
        #pragma unroll
        for (int oo = 0; oo < 16; ++oo) hb[oo] = (f16)acc[oo];
        const size_t base = ((size_t)(b * NT + n0 + n)) * NC + ob;
        *reinterpret_cast<f16x8*>(hp + base)     = *reinterpret_cast<const f16x8*>(&hb[0]);
        *reinterpret_cast<f16x8*>(hp + base + 8) = *reinterpret_cast<const f16x8*>(&hb[8]);
    } else {      // v: fp16, (C,N) layout
        const size_t vbase = (size_t)b * NC * NT + n0 + n;
        #pragma unroll
        for (int oo = 0; oo < 16; ++oo)
            vv[vbase + (size_t)(ob + oo) * NT] = (f16)acc[oo];
    }
}

// ---------------- kernel 2: flash attention (split-j, fp16) ----------------
// grid = splits * B * (N/64); each block does nTiles j-tiles from s*nTiles.
__global__ __launch_bounds__(256) void attn_fused(
    const f16* __restrict__ qh, const f16* __restrict__ kh,
    const f16* __restrict__ vv, float* __restrict__ out,
    f16* __restrict__ pacc, float* __restrict__ pm,
    float* __restrict__ pl, int nTiles, int direct)
{
    __shared__ f16 khs[64 * PADR];      // K-tile [j][c]
    __shared__ f16 vs_[64 * PADR];      // V-tile [c][j]
    __shared__ f16 ps[4][16 * PADR];    // per-wave P [i][j]

    const int t    = threadIdx.x;
    const int lane = t & 63;
    const int wv   = t >> 6;
    const int s    = blockIdx.x >> 8;
    const int b    = (blockIdx.x >> 6) & 3;
    const int i0   = (blockIdx.x & 63) << 6;
    const int c0   = lane & 15;   // A-row / B-col within subtile
    const int g    = lane >> 4;   // k-group 0..3

    // Q fragment (A-frag 16x16x32: lane row = lane&15, k = (lane>>4)*8+[0..7])
    f16x8 qf[2];
    {
        const size_t qoff = ((size_t)(b * NT + i0 + wv * 16 + c0)) * NC + g * 8;
        qf[0] = *reinterpret_cast<const f16x8*>(qh + qoff);
        qf[1] = *reinterpret_cast<const f16x8*>(qh + qoff + 32);
    }

    f32x4 acc[4] = {{0.f,0.f,0.f,0.f},{0.f,0.f,0.f,0.f},
                    {0.f,0.f,0.f,0.f},{0.f,0.f,0.f,0.f}};
    float m[4] = {-INFINITY, -INFINITY, -INFINITY, -INFINITY};
    float l[4] = {0.f, 0.f, 0.f, 0.f};

    // staging: 512 chunks of 8 fp16 per 64x64 tile; thread handles t and t+256
    const int ja = t >> 3,          ca = t & 7;
    const int jb2 = (t + 256) >> 3, cb2 = (t + 256) & 7;
    const f16* kh_g = kh + (size_t)b * NT * NC;
    const f16* v_g  = vv + (size_t)b * NC * NT;

    f16x8 st0, st1, st4, st5;
    auto stage_load = [&](int j0) {
        st0 = *reinterpret_cast<const f16x8*>(kh_g + (size_t)(j0 + ja) * NC + ca * 8);
        st1 = *reinterpret_cast<const f16x8*>(kh_g + (size_t)(j0 + jb2) * NC + cb2 * 8);
        st4 = *reinterpret_cast<const f16x8*>(v_g + (size_t)ja * NT + j0 + ca * 8);
        st5 = *reinterpret_cast<const f16x8*>(v_g + (size_t)jb2 * NT + j0 + cb2 * 8);
    };

    const int t0 = s * nTiles;
    stage_load(t0 * 64);

    for (int k = 0; k < nTiles; ++k) {
        const int jt = t0 + k;
        __syncthreads();   // previous tile's LDS reads complete
        *reinterpret_cast<f16x8*>(&khs[ja * PADR + ca * 8])   = st0;
        *reinterpret_cast<f16x8*>(&khs[jb2 * PADR + cb2 * 8]) = st1;
        *reinterpret_cast<f16x8*>(&vs_[ja * PADR + ca * 8])   = st4;
        *reinterpret_cast<f16x8*>(&vs_[jb2 * PADR + cb2 * 8]) = st5;
        __syncthreads();
        if (k + 1 < nTiles) stage_load((jt + 1) * 64);  // in flight under compute

        // ---- S = Q K^T (single-term fp16) ----
        f32x4 sreg[4] = {{0.f,0.f,0.f,0.f},{0.f,0.f,0.f,0.f},
                         {0.f,0.f,0.f,0.f},{0.f,0.f,0.f,0.f}};
        #pragma unroll
        for (int js = 0; js < 4; ++js) {
            #pragma unroll
            for (int kb = 0; kb < 2; ++kb) {
                const int roff = (js * 16 + c0) * PADR + kb * 32 + g * 8;
                const f16x8 bh = *reinterpret_cast<const f16x8*>(&khs[roff]);
                sreg[js] = __builtin_amdgcn_mfma_f32_16x16x32_f16(qf[kb], bh, sreg[js], 0, 0, 0);
            }
        }

        // ---- online softmax (D: col = lane&15 = key, row = g*4+r = query) ----
        float mt[4], pr[4][4], rs[4], sc[4];
        #pragma unroll
        for (int r = 0; r < 4; ++r)
            mt[r] = fmaxf(fmaxf(sreg[0][r], sreg[1][r]), fmaxf(sreg[2][r], sreg[3][r]));
        #pragma unroll
        for (int d = 1; d < 16; d <<= 1) {
            #pragma unroll
            for (int r = 0; r < 4; ++r)
                mt[r] = fmaxf(mt[r], __shfl_xor(mt[r], d));
        }
        #pragma unroll
        for (int r = 0; r < 4; ++r) {
            const float mn = fmaxf(m[r], mt[r]);
            sc[r] = __expf(m[r] - mn);
            m[r] = mn;
            rs[r] = 0.f;
            #pragma unroll
            for (int js = 0; js < 4; ++js) {
                pr[js][r] = __expf(sreg[js][r] - mn);
                rs[r] += pr[js][r];
            }
        }
        #pragma unroll
        for (int d = 1; d < 16; d <<= 1) {
            #pragma unroll
            for (int r = 0; r < 4; ++r)
                rs[r] += __shfl_xor(rs[r], d);
        }
        #pragma unroll
        for (int r = 0; r < 4; ++r) l[r] = l[r] * sc[r] + rs[r];
        #pragma unroll
        for (int cs = 0; cs < 4; ++cs)
            #pragma unroll
            for (int r = 0; r < 4; ++r)
                acc[cs][r] *= sc[r];

        // ---- P -> LDS (fp16), per-wave buffer (in-wave DS ordering) ----
        #pragma unroll
        for (int js = 0; js < 4; ++js)
            #pragma unroll
            for (int r = 0; r < 4; ++r)
                ps[wv][(g * 4 + r) * PADR + js * 16 + c0] = (f16)pr[js][r];

        // ---- O += P V ----
        #pragma unroll
        for (int jb = 0; jb < 2; ++jb) {
            const f16x8 ap = *reinterpret_cast<const f16x8*>(
                &ps[wv][c0 * PADR + jb * 32 + g * 8]);
            #pragma unroll
            for (int cs = 0; cs < 4; ++cs) {
                const f16x8 bvv = *reinterpret_cast<const f16x8*>(
                    &vs_[(cs * 16 + c0) * PADR + jb * 32 + g * 8]);
                acc[cs] = __builtin_amdgcn_mfma_f32_16x16x32_f16(ap, bvv, acc[cs], 0, 0, 0);
            }
        }
    }

    // ---- epilogue ----
    const int irow = i0 + wv * 16 + g * 4;
    float linv[4];
    #pragma unroll
    for (int r = 0; r < 4; ++r) linv[r] = 1.f / l[r];
    if (direct) {
        #pragma unroll
        for (int cs = 0; cs < 4; ++cs)
            #pragma unroll
            for (int r = 0; r < 4; ++r)
                out[(size_t)b * NC * NT + (size_t)(cs * 16 + c0) * NT + irow + r] =
                    acc[cs][r] * linv[r];
    } else {
        // store NORMALIZED partial o_s (fp16) + m,l (f32)
        const size_t pb = (size_t)(s * NB + b);
        #pragma unroll
        for (int cs = 0; cs < 4; ++cs)
            #pragma unroll
            for (int r = 0; r < 4; ++r)
                pacc[(pb * NC + cs * 16 + c0) * NT + irow + r] =
                    (f16)(acc[cs][r] * linv[r]);
        if (c0 == 0) {
            #pragma unroll
            for (int r = 0; r < 4; ++r) {
                pm[pb * NT + irow + r] = m[r];
                pl[pb * NT + irow + r] = l[r];
            }
        }
    }
}

// ---------------- kernel 3: merge split-j partials ----------------
// out = sum_s w_s l_s o_s / sum_s w_s l_s, w_s = exp(m_s - M).
__global__ __launch_bounds__(256) void merge_partials(
    const f16* __restrict__ pacc, const float* __restrict__ pm,
    const float* __restrict__ pl, float* __restrict__ out, int splits)
{
    const int t = threadIdx.x;
    const int i = ((blockIdx.x & 15) << 8) + t;
    const int c = (blockIdx.x >> 4) & 63;
    const int b = blockIdx.x >> 10;

    float ms[8];
    float M = -INFINITY;
    for (int s = 0; s < splits; ++s) {
        ms[s] = pm[(size_t)(s * NB + b) * NT + i];
        M = fmaxf(M, ms[s]);
    }
    float L = 0.f, A = 0.f;
    for (int s = 0; s < splits; ++s) {
        const float wl = __expf(ms[s] - M) * pl[(size_t)(s * NB + b) * NT + i];
        L += wl;
        A += wl * (float)pacc[((size_t)(s * NB + b) * NC + c) * NT + i];
    }
    out[((size_t)b * NC + c) * NT + i] = A / L;
}

extern "C" void kernel_launch(void* const* d_in, const int* in_sizes, int n_in,
                              void* d_out, int out_size, void* d_ws, size_t ws_size,
                              hipStream_t stream)
{
    const float* x  = (const float*)d_in[0];
    const float* Wq = (const float*)d_in[1];
    const float* bq = (const float*)d_in[2];
    const float* Wk = (const float*)d_in[3];
    const float* bk = (const float*)d_in[4];
    const float* Wv = (const float*)d_in[5];
    const float* bv = (const float*)d_in[6];
    float* out = (float*)d_out;

    // ws carve: qh,kh ((N,C) fp16) + v ((C,N) fp16) = 6 MB base,
    // then per-split: normalized o (fp16, S elems) + m,l (f32, NB*NT each).
    const size_t S = (size_t)NB * NT * NC;           // 1M elements
    const size_t base_bytes = 6 * S;                 // 3 fp16 arrays
    auto fits = [&](int sp) {
        return base_bytes + (size_t)sp * (2 * S + 2 * 4 * (size_t)NB * NT) <= ws_size;
    };
    const int splits = fits(4) ? 4 : fits(2) ? 2 : fits(1) ? 1 : 0;

    f16* qh = (f16*)d_ws;
    f16* kh = qh + S;
    f16* vv = kh + S;

    qkv_proj<<<3 * NB * (NT / 64), 256, 0, stream>>>(x, Wq, bq, Wk, bk, Wv, bv,
                                                     qh, kh, vv);

    if (splits == 0) {
        attn_fused<<<NB * (NT / 64), 256, 0, stream>>>(
            qh, kh, vv, out, nullptr, nullptr, nullptr, NT / 64, 1);
        return;
    }

    f16* pacc = vv + S;
    float* pm = (float*)(pacc + (size_t)splits * S);
    float* pl = pm + (size_t)splits * NB * NT;

    attn_fused<<<splits * NB * (NT / 64), 256, 0, stream>>>(
        qh, kh, vv, out, pacc, pm, pl, (NT / 64) / splits, 0);
    merge_partials<<<NB * NC * (NT / 256), 256, 0, stream>>>(pacc, pm, pl, out, splits);
}